// Round 17
// baseline (53.433 us; speedup 1.0000x reference)
//
#include <hip/hip_runtime.h>
#include <hip/hip_bf16.h>
#include <math.h>

#define NROW 256
#define DIM  65536
#define LSTR 264            // LDS row stride in ushorts (256 + 8 pad)
#define PSP  65600          // partial stride in ushorts (65536 + 64 pad)

typedef __attribute__((ext_vector_type(8))) short short8;
typedef __attribute__((ext_vector_type(4))) float f32x4;
typedef __attribute__((ext_vector_type(4))) float ef4;        // nt-compatible
typedef __attribute__((ext_vector_type(2))) unsigned int eu2;
typedef unsigned int       u32t;
typedef unsigned long long u64t;

__device__ __forceinline__ float bf2f(ushort h) {
    u32t u = ((u32t)h) << 16;
    return __builtin_bit_cast(float, u);
}
// packed fp32x2 -> bf16x2 (v_cvt_pk_bf16_f32, RNE)
__device__ __forceinline__ u32t pk2(float lo, float hi) {
    __hip_bfloat162 h = __float22bfloat162_rn(make_float2(lo, hi));
    u32t r; __builtin_memcpy(&r, &h, 4); return r;
}

// ---------------------------------------------------------------------------
// Split-K MFMA GEMM (= round 14, best known) + deterministic fixed-point
// diagonal accumulation (sq[i] = G[i][i]) via order-independent i64 atomics.
//  Stage:  wave w rows [w*32,+32); 1 instr = 64 lanes x 16 B = 1 KB
//          contiguous per row (nt - read once). cvt_pk -> ds_write_b64.
//  MFMA:   8 k-steps, 8 waves x (128x64), acc[8][4].
//  Epilogue: acc -> LDS transpose -> coalesced stores of whole columns.
//          G symmetric => storing G^T in plain [i][j] IS G. Diagonal quantized
//          to 2^-20 and atomicAdd'ed into sqacc (zeroed by memset pre-pass).
// ---------------------------------------------------------------------------
__global__ __launch_bounds__(512) void gemm_k(const float* __restrict__ E,
                                              ushort* __restrict__ part,
                                              u64t* __restrict__ sqacc) {
    const int s    = blockIdx.x;
    const int tid  = threadIdx.x;
    const int lane = tid & 63;
    const int wid  = tid >> 6;
    const int wr   = wid >> 2;          // 0..1 -> 128-row band
    const int wc   = wid & 3;           // 0..3 -> 64-col band
    const int r15  = lane & 15;
    const int kgi  = lane >> 4;         // 0..3 -> 8-k slice within k=32

    __shared__ ushort es[NROW][LSTR];   // 135 KB; staging, then transpose buf

    // ---------------- stage: coalesced 1 KB row reads (nt) ----------------
    {
        const int wrow = wid * 32;
        ef4 v[32];
        #pragma unroll
        for (int i = 0; i < 32; ++i) {
            const int row = wrow + i;
            v[i] = __builtin_nontemporal_load(
                (const ef4*)(E + ((size_t)row << 16)
                               + (size_t)s * 256 + lane * 4));
        }
        #pragma unroll
        for (int i = 0; i < 32; ++i) {
            const int row = wrow + i;
            eu2 wv;
            wv.x = pk2(v[i].x, v[i].y);
            wv.y = pk2(v[i].z, v[i].w);
            *(eu2*)&es[row][lane * 4] = wv;
        }
    }
    __syncthreads();

    // ---------------- MFMA: 8 k-steps of K=32 ----------------
    f32x4 acc[8][4];
    #pragma unroll
    for (int m = 0; m < 8; ++m)
        #pragma unroll
        for (int n = 0; n < 4; ++n) acc[m][n] = (f32x4){0.f, 0.f, 0.f, 0.f};

    #pragma unroll
    for (int kk = 0; kk < 8; ++kk) {
        const int ko = kk * 32 + kgi * 8;
        short8 af[8], bfr[4];
        #pragma unroll
        for (int m = 0; m < 8; ++m)
            af[m] = *(const short8*)&es[wr * 128 + m * 16 + r15][ko];
        #pragma unroll
        for (int n = 0; n < 4; ++n)
            bfr[n] = *(const short8*)&es[wc * 64 + n * 16 + r15][ko];
        #pragma unroll
        for (int m = 0; m < 8; ++m)
            #pragma unroll
            for (int n = 0; n < 4; ++n)
                acc[m][n] = __builtin_amdgcn_mfma_f32_16x16x32_bf16(
                    af[m], bfr[n], acc[m][n], 0, 0, 0);
    }

    __syncthreads();    // all frag reads done; es reusable as [col][row]

    // ---------------- epilogue: LDS transpose ----------------
    const int rq = (lane >> 4) * 4;     // row-quad base within 16-row block
    #pragma unroll
    for (int m = 0; m < 8; ++m)
        #pragma unroll
        for (int n = 0; n < 4; ++n) {
            const int col  = wc * 64 + n * 16 + r15;
            const int rowb = wr * 128 + m * 16 + rq;
            eu2 wv;
            wv.x = pk2(acc[m][n][0], acc[m][n][1]);
            wv.y = pk2(acc[m][n][2], acc[m][n][3]);
            *(eu2*)&es[col][rowb] = wv;   // es viewed as [col][row]
        }
    __syncthreads();

    // coalesced store-out: wave w streams cols [w*32, w*32+32)
    ushort* pb = part + (size_t)s * PSP;
    #pragma unroll
    for (int i = 0; i < 32; ++i) {
        const int col = wid * 32 + i;
        const eu2 q = *(const eu2*)&es[col][lane * 4];
        *(eu2*)(pb + col * 256 + lane * 4) = q;
    }

    // diagonal -> fixed-point atomic (order-independent => deterministic)
    if (tid < 256) {
        const float dv = bf2f(es[tid][tid]);
        atomicAdd(sqacc + tid, (u64t)(long long)llrintf(dv * 1048576.0f));
    }
}

// ---------------------------------------------------------------------------
// FUSED reduce + per-row softmax loss. Block i (512 threads, 8 waves):
// wave w sums partials s = 8u + w (u ascending, 512 B contiguous reads per
// partial, batched 16-deep) -> shred[w][j]; fixed pairwise tree across waves
// gives G[i][j]. sq from fixed-point sqacc. Softmax + masked numerator via
// wave shuffles; row loss quantized 2^-20, atomicAdd (order-independent);
// last block writes out. PSD term provably 0 (AM-GM, clip at 0) - omitted.
// ---------------------------------------------------------------------------
__global__ __launch_bounds__(512) void loss_k(const ushort* __restrict__ part,
                                              const u64t* __restrict__ sqacc,
                                              const int* __restrict__ labels,
                                              u64t* __restrict__ acc,
                                              u32t* __restrict__ cnt,
                                              float* __restrict__ out) {
    const int i   = blockIdx.x;
    const int tid = threadIdx.x;
    const int w   = tid >> 6;           // 0..7
    const int l   = tid & 63;

    __shared__ float shred[8][256];
    __shared__ float red0[4], red1[4];

    // reduce: 32 partials per wave, 16-deep batches
    float a0 = 0.f, a1 = 0.f, a2 = 0.f, a3 = 0.f;
    const ushort* base = part + (size_t)i * 256 + (size_t)l * 4;
    #pragma unroll
    for (int g = 0; g < 2; ++g) {
        eu2 v[16];
        #pragma unroll
        for (int u = 0; u < 16; ++u) {
            const int s = (g * 16 + u) * 8 + w;
            v[u] = *(const eu2*)(base + (size_t)s * PSP);
        }
        #pragma unroll
        for (int u = 0; u < 16; ++u) {
            a0 += bf2f((ushort)(v[u].x & 0xffffu));
            a1 += bf2f((ushort)(v[u].x >> 16));
            a2 += bf2f((ushort)(v[u].y & 0xffffu));
            a3 += bf2f((ushort)(v[u].y >> 16));
        }
    }
    shred[w][l * 4 + 0] = a0; shred[w][l * 4 + 1] = a1;
    shred[w][l * 4 + 2] = a2; shred[w][l * 4 + 3] = a3;
    __syncthreads();

    // softmax loss phase (first 256 threads act; j = tid)
    const int j = tid;
    const bool act = (tid < 256);
    float sc = -3.0e38f;
    bool diag = false;
    if (act) {
        const float Gij = ((shred[0][j] + shred[1][j]) + (shred[2][j] + shred[3][j]))
                        + ((shred[4][j] + shred[5][j]) + (shred[6][j] + shred[7][j]));
        const float sqi = (float)((double)(long long)sqacc[i] * (1.0 / 1048576.0));
        const float sqj = (float)((double)(long long)sqacc[j] * (1.0 / 1048576.0));
        const float d2 = fmaxf(sqi + sqj - 2.0f * Gij, 0.0f);
        diag = (j == i);
        sc = diag ? -3.0e38f : -sqrtf(d2);
    }

    float m = sc;
    #pragma unroll
    for (int off = 32; off; off >>= 1) m = fmaxf(m, __shfl_xor(m, off, 64));
    if (act && (j & 63) == 0) red0[j >> 6] = m;
    __syncthreads();
    m = fmaxf(fmaxf(red0[0], red0[1]), fmaxf(red0[2], red0[3]));

    const float p  = (act && !diag) ? expf(sc - m) : 0.0f;
    const float nm = (act && labels[j] == labels[i]) ? p : 0.0f;

    float zs = p, ns = nm;
    #pragma unroll
    for (int off = 32; off; off >>= 1) {
        zs += __shfl_xor(zs, off, 64);
        ns += __shfl_xor(ns, off, 64);
    }
    __syncthreads();    // WAR guard on red0
    if (act && (j & 63) == 0) { red0[j >> 6] = zs; red1[j >> 6] = ns; }
    __syncthreads();
    if (tid == 0) {
        const float Z = (red0[0] + red0[1]) + (red0[2] + red0[3]);
        const float N = (red1[0] + red1[1]) + (red1[2] + red1[3]);
        const float rl = logf(Z) - logf(N);          // >= 0 (N subset of Z)
        const long long q = llrintf(rl * 1048576.0f);
        atomicAdd(acc, (u64t)q);
        __threadfence();
        const u32t c = atomicAdd(cnt, 1u);
        if (c == NROW - 1) {
            __threadfence();
            const u64t tot = atomicAdd(acc, 0ull);
            out[0] = (float)((double)(long long)tot * (1.0 / 1048576.0) * 0.005);
        }
    }
}

extern "C" void kernel_launch(void* const* d_in, const int* in_sizes, int n_in,
                              void* d_out, int out_size, void* d_ws, size_t ws_size,
                              hipStream_t stream) {
    const float* E      = (const float*)d_in[0];
    const int*   labels = (const int*)d_in[1];
    float*       out    = (float*)d_out;

    ushort* part  = (ushort*)d_ws;                        // 256 * PSP ushorts
    u64t*   sqacc = (u64t*)((char*)d_ws + (size_t)256 * PSP * sizeof(ushort));
    u64t*   acc   = sqacc + 256;
    u32t*   cnt   = (u32t*)(acc + 1);

    // zero sqacc (2 KB) + acc (8 B) + cnt (4 B) - graph-capturable
    hipMemsetAsync((void*)sqacc, 0, 256 * sizeof(u64t) + 12, stream);

    gemm_k<<<256, 512, 0, stream>>>(E, part, sqacc);
    loss_k<<<NROW, 512, 0, stream>>>(part, sqacc, labels, acc, cnt, out);
}

// Round 18
// 43.460 us; speedup vs baseline: 1.2295x; 1.2295x over previous
//
#include <hip/hip_runtime.h>
#include <hip/hip_bf16.h>
#include <math.h>

#define NROW 256
#define DIM  65536
#define LSTR 264            // LDS row stride in ushorts (256 + 8 pad)
#define PSP  65600          // partial stride in ushorts (65536 + 64 pad)

typedef __attribute__((ext_vector_type(8))) short short8;
typedef __attribute__((ext_vector_type(4))) float f32x4;
typedef __attribute__((ext_vector_type(4))) float ef4;       // nt-compatible
typedef __attribute__((ext_vector_type(2))) unsigned int eu2; // nt-compatible
typedef unsigned int       u32t;
typedef unsigned long long u64t;

__device__ __forceinline__ float bf2f(ushort h) {
    u32t u = ((u32t)h) << 16;
    return __builtin_bit_cast(float, u);
}
// packed fp32x2 -> bf16x2 (v_cvt_pk_bf16_f32, RNE)
__device__ __forceinline__ u32t pk2(float lo, float hi) {
    __hip_bfloat162 h = __float22bfloat162_rn(make_float2(lo, hi));
    u32t r; __builtin_memcpy(&r, &h, 4); return r;
}

// ---------------------------------------------------------------------------
// Split-K MFMA GEMM, fully-coalesced (empirical best, = round 14).
//  Stage:  wave w rows [w*32,+32); 1 instr = 64 lanes x 16 B = 1 KB
//          contiguous per row (nt - read once). cvt_pk -> ds_write_b64.
//  MFMA:   8 k-steps, 8 waves x (128x64), acc[8][4].
//  Epilogue: acc -> LDS transpose -> coalesced nt stores of whole columns.
//          G symmetric => storing G^T in plain [i][j] IS G.
// ---------------------------------------------------------------------------
__global__ __launch_bounds__(512) void gemm_k(const float* __restrict__ E,
                                              ushort* __restrict__ part) {
    const int s    = blockIdx.x;
    const int tid  = threadIdx.x;
    const int lane = tid & 63;
    const int wid  = tid >> 6;
    const int wr   = wid >> 2;          // 0..1 -> 128-row band
    const int wc   = wid & 3;           // 0..3 -> 64-col band
    const int r15  = lane & 15;
    const int kgi  = lane >> 4;         // 0..3 -> 8-k slice within k=32

    __shared__ ushort es[NROW][LSTR];   // 135 KB; staging, then transpose buf

    // ---------------- stage: coalesced 1 KB row reads (nt) ----------------
    {
        const int wrow = wid * 32;
        ef4 v[32];
        #pragma unroll
        for (int i = 0; i < 32; ++i) {
            const int row = wrow + i;
            v[i] = __builtin_nontemporal_load(
                (const ef4*)(E + ((size_t)row << 16)
                               + (size_t)s * 256 + lane * 4));
        }
        #pragma unroll
        for (int i = 0; i < 32; ++i) {
            const int row = wrow + i;
            eu2 wv;
            wv.x = pk2(v[i].x, v[i].y);
            wv.y = pk2(v[i].z, v[i].w);
            *(eu2*)&es[row][lane * 4] = wv;
        }
    }
    __syncthreads();

    // ---------------- MFMA: 8 k-steps of K=32 ----------------
    f32x4 acc[8][4];
    #pragma unroll
    for (int m = 0; m < 8; ++m)
        #pragma unroll
        for (int n = 0; n < 4; ++n) acc[m][n] = (f32x4){0.f, 0.f, 0.f, 0.f};

    #pragma unroll
    for (int kk = 0; kk < 8; ++kk) {
        const int ko = kk * 32 + kgi * 8;
        short8 af[8], bfr[4];
        #pragma unroll
        for (int m = 0; m < 8; ++m)
            af[m] = *(const short8*)&es[wr * 128 + m * 16 + r15][ko];
        #pragma unroll
        for (int n = 0; n < 4; ++n)
            bfr[n] = *(const short8*)&es[wc * 64 + n * 16 + r15][ko];
        #pragma unroll
        for (int m = 0; m < 8; ++m)
            #pragma unroll
            for (int n = 0; n < 4; ++n)
                acc[m][n] = __builtin_amdgcn_mfma_f32_16x16x32_bf16(
                    af[m], bfr[n], acc[m][n], 0, 0, 0);
    }

    __syncthreads();    // all frag reads done; es reusable as [col][row]

    // ---------------- epilogue: LDS transpose ----------------
    const int rq = (lane >> 4) * 4;     // row-quad base within 16-row block
    #pragma unroll
    for (int m = 0; m < 8; ++m)
        #pragma unroll
        for (int n = 0; n < 4; ++n) {
            const int col  = wc * 64 + n * 16 + r15;
            const int rowb = wr * 128 + m * 16 + rq;
            eu2 wv;
            wv.x = pk2(acc[m][n][0], acc[m][n][1]);
            wv.y = pk2(acc[m][n][2], acc[m][n][3]);
            *(eu2*)&es[col][rowb] = wv;   // es viewed as [col][row]
        }
    __syncthreads();

    // coalesced nt store-out: wave w streams cols [w*32, w*32+32)
    ushort* pb = part + (size_t)s * PSP;
    #pragma unroll
    for (int i = 0; i < 32; ++i) {
        const int col = wid * 32 + i;
        const eu2 q = *(const eu2*)&es[col][lane * 4];
        __builtin_nontemporal_store(q, (eu2*)(pb + col * 256 + lane * 4));
    }
}

// ---------------------------------------------------------------------------
// Reduce 256 bf16 partials -> Gn (fp32, PLAIN [i*256+j] layout), nt reads.
// One position per thread; 8 fixed-order groups of 32 (deterministic tree).
// Also zeroes the fixed-point accumulator for row_loss (stream-ordered).
// ---------------------------------------------------------------------------
__global__ __launch_bounds__(256) void reduce_k(const ushort* __restrict__ part,
                                                float* __restrict__ Gn,
                                                u64t* __restrict__ acc,
                                                u32t* __restrict__ cnt) {
    if (blockIdx.x == 0 && threadIdx.x == 0) { *acc = 0ull; *cnt = 0u; }

    const int pos = blockIdx.x * 256 + threadIdx.x;   // 0..65535
    const ushort* base = part + pos;

    float g[8];
    #pragma unroll
    for (int q = 0; q < 8; ++q) {
        float a = 0.f;
        #pragma unroll
        for (int u = 0; u < 32; ++u)
            a += bf2f(__builtin_nontemporal_load(
                          base + (size_t)(q * 32 + u) * PSP));
        g[q] = a;
    }
    Gn[pos] = ((g[0] + g[1]) + (g[2] + g[3])) + ((g[4] + g[5]) + (g[6] + g[7]));
}

// ---------------------------------------------------------------------------
// Fused per-row softmax loss + deterministic final sum (fixed-point atomic,
// order-independent). PSD term provably 0 (AM-GM; clip at 0), omitted.
// ---------------------------------------------------------------------------
__global__ __launch_bounds__(256) void row_loss_k(const float* __restrict__ Gn,
                                                  const int* __restrict__ labels,
                                                  u64t* __restrict__ acc,
                                                  u32t* __restrict__ cnt,
                                                  float* __restrict__ out) {
    const int i = blockIdx.x;
    const int j = threadIdx.x;

    const float Gii = Gn[i * 256 + i];
    const float Gjj = Gn[j * 256 + j];
    const float Gij = Gn[i * 256 + j];
    const float d2 = fmaxf(Gii + Gjj - 2.0f * Gij, 0.0f);
    const bool diag = (j == i);
    const float sc = diag ? -3.0e38f : -sqrtf(d2);

    __shared__ float red0[4], red1[4];

    float m = sc;
    #pragma unroll
    for (int off = 32; off; off >>= 1) m = fmaxf(m, __shfl_xor(m, off, 64));
    const int w = j >> 6;
    if ((j & 63) == 0) red0[w] = m;
    __syncthreads();
    m = fmaxf(fmaxf(red0[0], red0[1]), fmaxf(red0[2], red0[3]));

    const float p  = diag ? 0.0f : expf(sc - m);
    const float nm = (labels[j] == labels[i]) ? p : 0.0f;

    float zs = p, ns = nm;
    #pragma unroll
    for (int off = 32; off; off >>= 1) {
        zs += __shfl_xor(zs, off, 64);
        ns += __shfl_xor(ns, off, 64);
    }
    __syncthreads();
    if ((j & 63) == 0) { red0[w] = zs; red1[w] = ns; }
    __syncthreads();
    if (j == 0) {
        const float Z = red0[0] + red0[1] + red0[2] + red0[3];
        const float N = red1[0] + red1[1] + red1[2] + red1[3];
        const float rl = logf(Z) - logf(N);          // >= 0 (N subset of Z)
        const long long q = llrintf(rl * 1048576.0f);
        atomicAdd(acc, (u64t)q);
        __threadfence();
        const u32t c = atomicAdd(cnt, 1u);
        if (c == NROW - 1) {
            __threadfence();
            const u64t tot = atomicAdd(acc, 0ull);
            out[0] = (float)((double)(long long)tot * (1.0 / 1048576.0) * 0.005);
        }
    }
}

extern "C" void kernel_launch(void* const* d_in, const int* in_sizes, int n_in,
                              void* d_out, int out_size, void* d_ws, size_t ws_size,
                              hipStream_t stream) {
    const float* E      = (const float*)d_in[0];
    const int*   labels = (const int*)d_in[1];
    float*       out    = (float*)d_out;

    ushort* part = (ushort*)d_ws;                         // 256 * PSP ushorts
    float*  Gn   = (float*)((char*)d_ws + (size_t)256 * PSP * sizeof(ushort));
    u64t*   acc  = (u64t*)(Gn + 65536);
    u32t*   cnt  = (u32t*)(acc + 1);

    gemm_k    <<<256, 512, 0, stream>>>(E, part);
    reduce_k  <<<256, 256, 0, stream>>>(part, Gn, acc, cnt);
    row_loss_k<<<NROW, 256, 0, stream>>>(Gn, labels, acc, cnt, out);
}